// Round 2
// baseline (3045.888 us; speedup 1.0000x reference)
//
#include <hip/hip_runtime.h>
#include <hip/hip_bf16.h>
#include <math.h>

#define B_N     4
#define L_N     2048
#define DMODEL  1024
#define DSTATE  128
#define DCONV   4
#define HEADDIM 64
#define CHUNK   256
#define DINNER  2048
#define NHEADS  32
#define CONVDIM 2304
#define DINPROJ 4384
#define NCHUNK  8
#define BL      (B_N*L_N)

typedef unsigned short ushort_t;
typedef unsigned int   uint_t;

__device__ __forceinline__ float bfbits2f(ushort_t u){
    union { uint_t i; float f; } v; v.i = ((uint_t)u) << 16; return v.f;
}
__device__ __forceinline__ float bflo(uint_t u){
    union { uint_t i; float f; } v; v.i = u << 16; return v.f;
}
__device__ __forceinline__ float bfhi(uint_t u){
    union { uint_t i; float f; } v; v.i = u & 0xFFFF0000u; return v.f;
}

// ---------------------------------------------------------------------------
// K1: zxbcdt = u @ W_in^T, fused split epilogue.
// A = u [BL][1024] f32, B = W_in [4384][1024] f32 (both K-contiguous, NT gemm)
// ---------------------------------------------------------------------------
#define G_BM 128
#define G_BN 128
#define G_BK 16

__global__ __launch_bounds__(256) void gemm_inproj(
    const float* __restrict__ u, const float* __restrict__ W,
    const float* __restrict__ dt_bias,
    __hip_bfloat16* __restrict__ z, __hip_bfloat16* __restrict__ xbc_raw,
    float* __restrict__ dtp)
{
    __shared__ float As[G_BK][G_BM+4];
    __shared__ float Bs[G_BK][G_BN+4];
    int m0 = blockIdx.x * G_BM;
    int n0 = blockIdx.y * G_BN;
    int t  = threadIdx.x;
    int tx = t & 15, ty = t >> 4;
    int lr = t >> 1, lk = (t & 1) * 8;

    float acc[8][8];
    #pragma unroll
    for (int i=0;i<8;i++) {
        #pragma unroll
        for (int j=0;j<8;j++) acc[i][j]=0.f;
    }

    for (int k0 = 0; k0 < DMODEL; k0 += G_BK) {
        const float4* ap = (const float4*)(u + (size_t)(m0+lr)*DMODEL + k0 + lk);
        float4 a0 = ap[0], a1 = ap[1];
        int nrow = n0 + lr;
        float4 b0 = make_float4(0,0,0,0), b1 = make_float4(0,0,0,0);
        if (nrow < DINPROJ) {
            const float4* bp = (const float4*)(W + (size_t)nrow*DMODEL + k0 + lk);
            b0 = bp[0]; b1 = bp[1];
        }
        __syncthreads();
        As[lk+0][lr]=a0.x; As[lk+1][lr]=a0.y; As[lk+2][lr]=a0.z; As[lk+3][lr]=a0.w;
        As[lk+4][lr]=a1.x; As[lk+5][lr]=a1.y; As[lk+6][lr]=a1.z; As[lk+7][lr]=a1.w;
        Bs[lk+0][lr]=b0.x; Bs[lk+1][lr]=b0.y; Bs[lk+2][lr]=b0.z; Bs[lk+3][lr]=b0.w;
        Bs[lk+4][lr]=b1.x; Bs[lk+5][lr]=b1.y; Bs[lk+6][lr]=b1.z; Bs[lk+7][lr]=b1.w;
        __syncthreads();
        #pragma unroll
        for (int k=0;k<G_BK;k++){
            const float4* A4 = (const float4*)&As[k][ty*8];
            const float4* B4 = (const float4*)&Bs[k][tx*8];
            float4 av0 = A4[0], av1 = A4[1];
            float4 bv0 = B4[0], bv1 = B4[1];
            float ar[8] = {av0.x,av0.y,av0.z,av0.w,av1.x,av1.y,av1.z,av1.w};
            float br[8] = {bv0.x,bv0.y,bv0.z,bv0.w,bv1.x,bv1.y,bv1.z,bv1.w};
            #pragma unroll
            for (int i=0;i<8;i++)
                #pragma unroll
                for (int j=0;j<8;j++)
                    acc[i][j] += ar[i]*br[j];
        }
    }
    // epilogue: route columns to z / xbc_raw / softplus(dt)
    #pragma unroll
    for (int i=0;i<8;i++){
        int m = m0 + ty*8 + i;
        int b = m >> 11;          // L=2048
        int l = m & (L_N-1);
        #pragma unroll
        for (int j=0;j<8;j++){
            int n = n0 + tx*8 + j;
            if (n >= DINPROJ) continue;
            float v = acc[i][j];
            if (n < DINNER) {
                z[(size_t)m*DINNER + n] = __float2bfloat16(v);
            } else if (n < DINNER + CONVDIM) {
                xbc_raw[(size_t)m*CONVDIM + (n - DINNER)] = __float2bfloat16(v);
            } else {
                int h = n - (DINNER + CONVDIM);
                float x = v + dt_bias[h];
                float sp = (x > 15.f) ? x : log1pf(__expf(x));
                dtp[((size_t)b*NHEADS + h)*L_N + l] = sp;
            }
        }
    }
}

// ---------------------------------------------------------------------------
// K2: causal depthwise conv1d (width 4) + bias + SiLU
// ---------------------------------------------------------------------------
__global__ __launch_bounds__(256) void conv_silu(
    const __hip_bfloat16* __restrict__ xraw,
    const float* __restrict__ cw, const float* __restrict__ cb,
    __hip_bfloat16* __restrict__ xout)
{
    int idx = blockIdx.x*256 + threadIdx.x;
    if (idx >= BL*CONVDIM) return;
    int c  = idx % CONVDIM;
    int ml = idx / CONVDIM;
    int b  = ml / L_N;
    int l  = ml % L_N;
    const ushort_t* xr = (const ushort_t*)xraw;
    float acc = cb[c];
    #pragma unroll
    for (int k=0;k<DCONV;k++){
        int li = l - (DCONV-1) + k;
        if (li >= 0)
            acc += cw[c*DCONV + k] * bfbits2f(xr[((size_t)b*L_N + li)*CONVDIM + c]);
    }
    float s = acc / (1.f + __expf(-acc));
    xout[idx] = __float2bfloat16(s);
}

// ---------------------------------------------------------------------------
// K3: dA = dt*A; inclusive cumsum within each chunk  (block per (b,h,c))
// ---------------------------------------------------------------------------
__global__ __launch_bounds__(256) void dt_cumsum(
    const float* __restrict__ dtp, const float* __restrict__ A_log,
    float* __restrict__ dAcs)
{
    int blk = blockIdx.x;
    int c  = blk % NCHUNK;
    int bh = blk / NCHUNK;     // b*32 + h
    int h  = bh & (NHEADS-1);
    int t  = threadIdx.x;
    float A = -__expf(A_log[h]);
    __shared__ float sm[CHUNK];
    float v = dtp[(size_t)bh*L_N + c*CHUNK + t] * A;
    sm[t] = v;
    __syncthreads();
    for (int off=1; off<CHUNK; off<<=1){
        float add = (t >= off) ? sm[t-off] : 0.f;
        __syncthreads();
        sm[t] += add;
        __syncthreads();
    }
    dAcs[(size_t)bh*L_N + c*CHUNK + t] = sm[t];
}

// ---------------------------------------------------------------------------
// K4: scoresT[b,c][j][i] = sum_n B[j,n]*C[i,n]   (block per (b,c))
// ---------------------------------------------------------------------------
__global__ __launch_bounds__(256) void bc_scores(
    const __hip_bfloat16* __restrict__ xbc, float* __restrict__ scoresT)
{
    __shared__ uint_t Bsu[CHUNK][DSTATE/2 + 1];   // 66.5 KB
    int bc = blockIdx.x;
    int t  = threadIdx.x;
    const ushort_t* xb = (const ushort_t*)xbc;
    for (int rep=0; rep<64; rep++){
        int idx = rep*256 + t;
        int row = idx >> 6, n2 = idx & 63;
        Bsu[row][n2] = *(const uint_t*)&xb[((size_t)bc*CHUNK + row)*CONVDIM + DINNER + 2*n2];
    }
    __syncthreads();
    int i = t;
    const uint_t* Crow = (const uint_t*)(xb + ((size_t)bc*CHUNK + i)*CONVDIM + DINNER + DSTATE);
    for (int j0=0; j0<CHUNK; j0+=8){
        float acc[8] = {0,0,0,0,0,0,0,0};
        for (int n2=0; n2<DSTATE/2; n2++){
            uint_t cu = Crow[n2];
            float c0 = bflo(cu), c1 = bfhi(cu);
            #pragma unroll
            for (int jj=0;jj<8;jj++){
                uint_t bu = Bsu[j0+jj][n2];
                acc[jj] += c0*bflo(bu) + c1*bfhi(bu);
            }
        }
        #pragma unroll
        for (int jj=0;jj<8;jj++)
            scoresT[((size_t)bc*CHUNK + j0+jj)*CHUNK + i] = acc[jj];
    }
}

// ---------------------------------------------------------------------------
// K5: Y_diag + D*x  (block per (b*c, h); thread = row i)
// ---------------------------------------------------------------------------
__global__ __launch_bounds__(256) void ssd_diag(
    const __hip_bfloat16* __restrict__ xbc,
    const float* __restrict__ dtp, const float* __restrict__ dAcs,
    const float* __restrict__ scoresT, const float* __restrict__ D_param,
    float* __restrict__ yh)
{
    __shared__ float xs[CHUNK][HEADDIM+4];  // stride 68 to spread banks
    __shared__ float dt_s[CHUNK];
    __shared__ float da_s[CHUNK];
    int bc = blockIdx.x, h = blockIdx.y;
    int b = bc >> 3, c = bc & 7;
    int t = threadIdx.x;
    const ushort_t* xb = (const ushort_t*)xbc;
    for (int rep=0; rep<64; rep++){
        int idx = rep*256 + t;
        int row = idx >> 6, pp = idx & 63;
        xs[row][pp] = bfbits2f(xb[((size_t)bc*CHUNK + row)*CONVDIM + h*HEADDIM + pp]);
    }
    dt_s[t] = dtp[((size_t)b*NHEADS + h)*L_N + c*CHUNK + t];
    da_s[t] = dAcs[((size_t)b*NHEADS + h)*L_N + c*CHUNK + t];
    __syncthreads();
    int i = t;
    float acc[64];
    #pragma unroll
    for (int q=0;q<64;q++) acc[q]=0.f;
    float myda = da_s[i];
    const float* srow = scoresT + (size_t)bc*CHUNK*CHUNK + i;
    for (int j=0; j<=i; j++){
        float w = __expf(myda - da_s[j]) * dt_s[j] * srow[(size_t)j*CHUNK];
        const float4* xr = (const float4*)&xs[j][0];
        #pragma unroll
        for (int q=0;q<16;q++){
            float4 xv = xr[q];
            acc[4*q+0] += w*xv.x; acc[4*q+1] += w*xv.y;
            acc[4*q+2] += w*xv.z; acc[4*q+3] += w*xv.w;
        }
    }
    float Dh = D_param[h];
    size_t row = ((size_t)bc*CHUNK + i)*DINNER + (size_t)h*HEADDIM;
    #pragma unroll
    for (int q=0;q<64;q++) yh[row+q] = acc[q] + Dh*xs[i][q];
}

// ---------------------------------------------------------------------------
// K6: chunk states[b,c,h,p,n] = sum_j B[j,n]*exp(da_last-da[j])*dt[j]*x[j,p]
// ---------------------------------------------------------------------------
__global__ __launch_bounds__(256) void ssd_states(
    const __hip_bfloat16* __restrict__ xbc,
    const float* __restrict__ dtp, const float* __restrict__ dAcs,
    float* __restrict__ states)
{
    __shared__ uint_t Bsu[CHUNK][DSTATE/2];   // 64 KB
    __shared__ float dt_s[CHUNK];
    __shared__ float da_s[CHUNK];
    int bc = blockIdx.x, h = blockIdx.y;
    int b = bc >> 3, c = bc & 7;
    int t = threadIdx.x;
    const ushort_t* xb = (const ushort_t*)xbc;
    for (int rep=0; rep<64; rep++){
        int idx = rep*256 + t;
        int row = idx >> 6, n2 = idx & 63;
        Bsu[row][n2] = *(const uint_t*)&xb[((size_t)bc*CHUNK + row)*CONVDIM + DINNER + 2*n2];
    }
    dt_s[t] = dtp[((size_t)b*NHEADS + h)*L_N + c*CHUNK + t];
    da_s[t] = dAcs[((size_t)b*NHEADS + h)*L_N + c*CHUNK + t];
    __syncthreads();
    int p = t & 63, ng = t >> 6;
    float sacc[32];
    #pragma unroll
    for (int q=0;q<32;q++) sacc[q]=0.f;
    float last = da_s[CHUNK-1];
    for (int j=0;j<CHUNK;j++){
        float xv = bfbits2f(xb[((size_t)bc*CHUNK + j)*CONVDIM + h*HEADDIM + p]);
        float coef = __expf(last - da_s[j]) * dt_s[j] * xv;
        const uint_t* br = &Bsu[j][ng*16];
        #pragma unroll
        for (int k2=0;k2<16;k2++){
            uint_t bu = br[k2];
            sacc[2*k2]   += coef*bflo(bu);
            sacc[2*k2+1] += coef*bfhi(bu);
        }
    }
    size_t sb = (((size_t)bc*NHEADS + h)*HEADDIM + p)*DSTATE + ng*32;
    #pragma unroll
    for (int q=0;q<32;q++) states[sb+q] = sacc[q];
}

// ---------------------------------------------------------------------------
// K7: inter-chunk scan (sequential over 8 chunks), in-place: states -> prev
// ---------------------------------------------------------------------------
__global__ __launch_bounds__(256) void scan_states(
    float* __restrict__ states, const float* __restrict__ dAcs)
{
    int idx = blockIdx.x*256 + threadIdx.x;   // ((b*32+h)*64+p)*128+n
    int n  = idx & 127;
    int p  = (idx >> 7) & 63;
    int bh = idx >> 13;
    int b  = bh >> 5, h = bh & 31;
    float carry = 0.f;
    for (int c=0;c<NCHUNK;c++){
        size_t off = (((size_t)((b*NCHUNK + c)*NHEADS + h))*HEADDIM + p)*DSTATE + n;
        float s = states[off];
        states[off] = carry;
        float cd = __expf(dAcs[((size_t)b*NHEADS + h)*L_N + c*CHUNK + (CHUNK-1)]);
        carry = carry * cd + s;
    }
}

// ---------------------------------------------------------------------------
// K8: Y_off[i,p] = exp(da[i]) * sum_n C[i,n]*prev[p,n];  yh += Y_off
// ---------------------------------------------------------------------------
__global__ __launch_bounds__(256) void ssd_off(
    const __hip_bfloat16* __restrict__ xbc,
    const float* __restrict__ dAcs, const float* __restrict__ states,
    float* __restrict__ yh)
{
    __shared__ float ps[HEADDIM][DSTATE];   // 32 KB
    int bc = blockIdx.x, h = blockIdx.y;
    int b = bc >> 3, c = bc & 7;
    int t = threadIdx.x;
    const float* sb = states + (size_t)(bc*NHEADS + h)*HEADDIM*DSTATE;
    for (int rep=0; rep<32; rep++){
        int idx = rep*256 + t;
        ((float*)ps)[idx] = sb[idx];
    }
    __syncthreads();
    int i = t;
    float acc[64];
    #pragma unroll
    for (int q=0;q<64;q++) acc[q]=0.f;
    const ushort_t* xb = (const ushort_t*)xbc;
    const uint_t* Crow = (const uint_t*)(xb + ((size_t)bc*CHUNK + i)*CONVDIM + DINNER + DSTATE);
    #pragma unroll
    for (int nb=0; nb<4; nb++){
        float cv[32];
        #pragma unroll
        for (int k2=0;k2<16;k2++){
            uint_t u = Crow[nb*16 + k2];
            cv[2*k2] = bflo(u); cv[2*k2+1] = bfhi(u);
        }
        #pragma unroll
        for (int p=0;p<64;p++){
            const float4* pr = (const float4*)&ps[p][nb*32];
            float s = 0.f;
            #pragma unroll
            for (int k4=0;k4<8;k4++){
                float4 v = pr[k4];
                s += cv[4*k4]*v.x + cv[4*k4+1]*v.y + cv[4*k4+2]*v.z + cv[4*k4+3]*v.w;
            }
            acc[p] += s;
        }
    }
    float scale = __expf(dAcs[((size_t)b*NHEADS + h)*L_N + c*CHUNK + i]);
    size_t row = ((size_t)bc*CHUNK + i)*DINNER + (size_t)h*HEADDIM;
    #pragma unroll
    for (int q=0;q<64;q++) yh[row+q] += scale*acc[q];
}

// ---------------------------------------------------------------------------
// K9: g = yh * silu(z); RMSNorm(g)*norm_w  -> bf16 g  (block per token row)
// ---------------------------------------------------------------------------
__global__ __launch_bounds__(256) void gate_norm(
    const float* __restrict__ yh, const __hip_bfloat16* __restrict__ z,
    const float* __restrict__ norm_w, __hip_bfloat16* __restrict__ g)
{
    int row = blockIdx.x;
    int t = threadIdx.x;
    const float* yr = yh + (size_t)row*DINNER;
    const ushort_t* zr = (const ushort_t*)z + (size_t)row*DINNER;
    float v[8];
    float ss = 0.f;
    #pragma unroll
    for (int r=0;r<8;r++){
        int d = r*256 + t;
        float zv = bfbits2f(zr[d]);
        float gv = yr[d] * (zv / (1.f + __expf(-zv)));
        v[r] = gv; ss += gv*gv;
    }
    #pragma unroll
    for (int off=32; off>=1; off>>=1) ss += __shfl_xor(ss, off);
    __shared__ float red[4];
    if ((t & 63) == 0) red[t >> 6] = ss;
    __syncthreads();
    float tot = red[0]+red[1]+red[2]+red[3];
    float scale = rsqrtf(tot * (1.f/DINNER) + 1e-5f);
    __hip_bfloat16* gr = g + (size_t)row*DINNER;
    #pragma unroll
    for (int r=0;r<8;r++){
        int d = r*256 + t;
        gr[d] = __float2bfloat16(v[r]*scale*norm_w[d]);
    }
}

// ---------------------------------------------------------------------------
// K10: out = g @ W_out^T   (g bf16 [BL][2048], W_out f32 [1024][2048])
// ---------------------------------------------------------------------------
__global__ __launch_bounds__(256) void gemm_out(
    const __hip_bfloat16* __restrict__ g, const float* __restrict__ Wout,
    float* __restrict__ out)
{
    __shared__ float As[G_BK][G_BM+4];
    __shared__ float Bs[G_BK][G_BN+4];
    int m0 = blockIdx.x * G_BM;
    int n0 = blockIdx.y * G_BN;
    int t  = threadIdx.x;
    int tx = t & 15, ty = t >> 4;
    int lr = t >> 1, lk = (t & 1) * 8;

    float acc[8][8];
    #pragma unroll
    for (int i=0;i<8;i++) {
        #pragma unroll
        for (int j=0;j<8;j++) acc[i][j]=0.f;
    }

    const ushort_t* gb = (const ushort_t*)g;
    for (int k0 = 0; k0 < DINNER; k0 += G_BK) {
        uint4 av = *(const uint4*)(gb + (size_t)(m0+lr)*DINNER + k0 + lk);
        const float4* bp = (const float4*)(Wout + (size_t)(n0+lr)*DINNER + k0 + lk);
        float4 b0 = bp[0], b1 = bp[1];
        __syncthreads();
        As[lk+0][lr]=bflo(av.x); As[lk+1][lr]=bfhi(av.x);
        As[lk+2][lr]=bflo(av.y); As[lk+3][lr]=bfhi(av.y);
        As[lk+4][lr]=bflo(av.z); As[lk+5][lr]=bfhi(av.z);
        As[lk+6][lr]=bflo(av.w); As[lk+7][lr]=bfhi(av.w);
        Bs[lk+0][lr]=b0.x; Bs[lk+1][lr]=b0.y; Bs[lk+2][lr]=b0.z; Bs[lk+3][lr]=b0.w;
        Bs[lk+4][lr]=b1.x; Bs[lk+5][lr]=b1.y; Bs[lk+6][lr]=b1.z; Bs[lk+7][lr]=b1.w;
        __syncthreads();
        #pragma unroll
        for (int k=0;k<G_BK;k++){
            const float4* A4 = (const float4*)&As[k][ty*8];
            const float4* B4 = (const float4*)&Bs[k][tx*8];
            float4 av0 = A4[0], av1 = A4[1];
            float4 bv0 = B4[0], bv1 = B4[1];
            float ar[8] = {av0.x,av0.y,av0.z,av0.w,av1.x,av1.y,av1.z,av1.w};
            float br[8] = {bv0.x,bv0.y,bv0.z,bv0.w,bv1.x,bv1.y,bv1.z,bv1.w};
            #pragma unroll
            for (int i=0;i<8;i++)
                #pragma unroll
                for (int j=0;j<8;j++)
                    acc[i][j] += ar[i]*br[j];
        }
    }
    #pragma unroll
    for (int i=0;i<8;i++){
        int m = m0 + ty*8 + i;
        #pragma unroll
        for (int j=0;j<8;j++)
            out[(size_t)m*DMODEL + n0 + tx*8 + j] = acc[i][j];
    }
}

// ---------------------------------------------------------------------------
extern "C" void kernel_launch(void* const* d_in, const int* in_sizes, int n_in,
                              void* d_out, int out_size, void* d_ws, size_t ws_size,
                              hipStream_t stream)
{
    const float* u       = (const float*)d_in[0];
    const float* W_in    = (const float*)d_in[1];
    const float* conv_w  = (const float*)d_in[2];
    const float* conv_b  = (const float*)d_in[3];
    const float* dt_bias = (const float*)d_in[4];
    const float* A_log   = (const float*)d_in[5];
    const float* D_param = (const float*)d_in[6];
    const float* norm_w  = (const float*)d_in[7];
    const float* W_out   = (const float*)d_in[8];
    float* out = (float*)d_out;

    char* p = (char*)d_ws;
    auto take = [&](size_t n){ char* r = p; p += (n + 255) & ~(size_t)255; return r; };

    __hip_bfloat16* z       = (__hip_bfloat16*)take((size_t)BL*DINNER*2);
    __hip_bfloat16* xbc_raw = (__hip_bfloat16*)take((size_t)BL*CONVDIM*2);
    __hip_bfloat16* xbc     = (__hip_bfloat16*)take((size_t)BL*CONVDIM*2);
    float* dtp     = (float*)take((size_t)BL*NHEADS*4);
    float* dAcs    = (float*)take((size_t)BL*NHEADS*4);
    float* scoresT = (float*)take((size_t)B_N*NCHUNK*CHUNK*CHUNK*4);
    float* states  = (float*)take((size_t)B_N*NCHUNK*NHEADS*HEADDIM*DSTATE*4);
    float* yh      = (float*)take((size_t)BL*DINNER*4);
    __hip_bfloat16* g = z;   // alias: z dead after gate_norm's elementwise read

    gemm_inproj<<<dim3(BL/G_BM, (DINPROJ + G_BN - 1)/G_BN), 256, 0, stream>>>(
        u, W_in, dt_bias, z, xbc_raw, dtp);
    conv_silu<<<dim3((BL*CONVDIM)/256), 256, 0, stream>>>(xbc_raw, conv_w, conv_b, xbc);
    dt_cumsum<<<dim3(B_N*NHEADS*NCHUNK), 256, 0, stream>>>(dtp, A_log, dAcs);
    bc_scores<<<dim3(B_N*NCHUNK), 256, 0, stream>>>(xbc, scoresT);
    ssd_diag<<<dim3(B_N*NCHUNK, NHEADS), 256, 0, stream>>>(xbc, dtp, dAcs, scoresT, D_param, yh);
    ssd_states<<<dim3(B_N*NCHUNK, NHEADS), 256, 0, stream>>>(xbc, dtp, dAcs, states);
    scan_states<<<dim3((B_N*NHEADS*HEADDIM*DSTATE)/256), 256, 0, stream>>>(states, dAcs);
    ssd_off<<<dim3(B_N*NCHUNK, NHEADS), 256, 0, stream>>>(xbc, dAcs, states, yh);
    gate_norm<<<dim3(BL), 256, 0, stream>>>(yh, z, norm_w, g);
    gemm_out<<<dim3(BL/G_BM, DMODEL/G_BN), 256, 0, stream>>>(g, W_out, out);
}

// Round 3
// 1892.684 us; speedup vs baseline: 1.6093x; 1.6093x over previous
//
#include <hip/hip_runtime.h>
#include <hip/hip_bf16.h>
#include <math.h>

#define B_N     4
#define L_N     2048
#define DMODEL  1024
#define DSTATE  128
#define DCONV   4
#define HEADDIM 64
#define CHUNK   256
#define DINNER  2048
#define NHEADS  32
#define CONVDIM 2304
#define DINPROJ 4384
#define NCHUNK  8
#define BL      (B_N*L_N)

typedef unsigned short ushort_t;
typedef unsigned int   uint_t;

typedef __attribute__((ext_vector_type(8))) short bf16x8;
typedef __attribute__((ext_vector_type(4))) float f32x4;

__device__ __forceinline__ float bfbits2f(ushort_t u){
    union { uint_t i; float f; } v; v.i = ((uint_t)u) << 16; return v.f;
}
__device__ __forceinline__ float bflo(uint_t u){
    union { uint_t i; float f; } v; v.i = u << 16; return v.f;
}
__device__ __forceinline__ float bfhi(uint_t u){
    union { uint_t i; float f; } v; v.i = u & 0xFFFF0000u; return v.f;
}
__device__ __forceinline__ ushort_t f2bf(float f){
    union { float f; uint_t i; } v; v.f = f;
    uint_t r = v.i + 0x7FFF + ((v.i >> 16) & 1);
    return (ushort_t)(r >> 16);
}
__device__ __forceinline__ void gload_lds16(const void* g, void* l){
    __builtin_amdgcn_global_load_lds(
        (const __attribute__((address_space(1))) unsigned int*)g,
        (__attribute__((address_space(3))) unsigned int*)l, 16, 0, 0);
}

// ---------------------------------------------------------------------------
// K0: f32 -> bf16 convert (8 elems/thread)
// ---------------------------------------------------------------------------
__global__ __launch_bounds__(256) void cvt_bf16(
    const float* __restrict__ in, ushort_t* __restrict__ out, int n8)
{
    int i = blockIdx.x*256 + threadIdx.x;
    if (i >= n8) return;
    const float4* p = (const float4*)(in + (size_t)i*8);
    float4 a = p[0], b = p[1];
    ushort_t o[8] = { f2bf(a.x), f2bf(a.y), f2bf(a.z), f2bf(a.w),
                      f2bf(b.x), f2bf(b.y), f2bf(b.z), f2bf(b.w) };
    *(uint4*)(out + (size_t)i*8) = *(const uint4*)o;
}

// ---------------------------------------------------------------------------
// K1a: dt columns (last 32 of W_in) in fp32: dtp = softplus(u @ Wdt^T + bias)
// ---------------------------------------------------------------------------
__global__ __launch_bounds__(256) void dt_gemm(
    const float* __restrict__ u, const float* __restrict__ W,
    const float* __restrict__ dt_bias, float* __restrict__ dtp)
{
    int idx = blockIdx.x*256 + threadIdx.x;   // m*32 + h
    int m = idx >> 5, h = idx & 31;
    const float4* ur = (const float4*)(u + (size_t)m*DMODEL);
    const float4* wr = (const float4*)(W + (size_t)(DINNER+CONVDIM+h)*DMODEL);
    float acc = 0.f;
    #pragma unroll 4
    for (int k=0;k<DMODEL/4;k++){
        float4 a = ur[k], b = wr[k];
        acc += a.x*b.x + a.y*b.y + a.z*b.z + a.w*b.w;
    }
    float x = acc + dt_bias[h];
    float sp = (x > 15.f) ? x : log1pf(__expf(x));
    int b = m >> 11, l = m & (L_N-1);
    dtp[((size_t)b*NHEADS + h)*L_N + l] = sp;
}

// ---------------------------------------------------------------------------
// K1b: bf16 MFMA GEMM, C = A @ B^T. 128x128 tile, BK=32, 4 waves (m97 struct).
// A [M][KDIM] bf16, B [N][KDIM] bf16. EPI=0: f32 out [M][1024].
// EPI=1: in-proj split (cols<2048 -> z bf16, else xbc_raw bf16; N=4352 total).
// ---------------------------------------------------------------------------
template<int KDIM, int EPI>
__global__ __launch_bounds__(256) void gemm_bt_mfma(
    const ushort_t* __restrict__ A, const ushort_t* __restrict__ B,
    float* __restrict__ outf, ushort_t* __restrict__ z, ushort_t* __restrict__ xbc)
{
    __shared__ __align__(16) ushort_t Asl[128*32];
    __shared__ __align__(16) ushort_t Bsl[128*32];
    int m0 = blockIdx.x*128, n0 = blockIdx.y*128;
    int t = threadIdx.x;
    int l = t & 63, w = t >> 6;
    int wr = w >> 1, wc = w & 1;
    int lr16 = l & 15, kb = l >> 4;
    int srow = t >> 2, skc = (t & 3)*8;

    f32x4 acc[4][4];
    #pragma unroll
    for (int m=0;m<4;m++){
        #pragma unroll
        for (int n=0;n<4;n++) acc[m][n] = (f32x4){0.f,0.f,0.f,0.f};
    }

    for (int k0=0; k0<KDIM; k0+=32){
        gload_lds16(A + (size_t)(m0+srow)*KDIM + k0 + skc,      &Asl[t*8]);
        gload_lds16(A + (size_t)(m0+64+srow)*KDIM + k0 + skc,   &Asl[2048 + t*8]);
        gload_lds16(B + (size_t)(n0+srow)*KDIM + k0 + skc,      &Bsl[t*8]);
        gload_lds16(B + (size_t)(n0+64+srow)*KDIM + k0 + skc,   &Bsl[2048 + t*8]);
        __syncthreads();
        bf16x8 af[4], bfr[4];
        #pragma unroll
        for (int m=0;m<4;m++) af[m]  = *(const bf16x8*)&Asl[(wr*64+m*16+lr16)*32 + kb*8];
        #pragma unroll
        for (int n=0;n<4;n++) bfr[n] = *(const bf16x8*)&Bsl[(wc*64+n*16+lr16)*32 + kb*8];
        #pragma unroll
        for (int m=0;m<4;m++){
            #pragma unroll
            for (int n=0;n<4;n++)
                acc[m][n] = __builtin_amdgcn_mfma_f32_16x16x32_bf16(af[m], bfr[n], acc[m][n], 0, 0, 0);
        }
        __syncthreads();
    }

    // C/D layout: col = lane&15, row = (lane>>4)*4 + q   [m89/m91 verified]
    #pragma unroll
    for (int m=0;m<4;m++){
        int rbase = m0 + wr*64 + m*16 + (l>>4)*4;
        #pragma unroll
        for (int n=0;n<4;n++){
            int gcol = n0 + wc*64 + n*16 + lr16;
            f32x4 v = acc[m][n];
            #pragma unroll
            for (int q=0;q<4;q++){
                int row = rbase + q;
                if (EPI == 0) {
                    outf[(size_t)row*DMODEL + gcol] = v[q];
                } else {
                    if (gcol < DINNER)
                        z[(size_t)row*DINNER + gcol] = f2bf(v[q]);
                    else
                        xbc[(size_t)row*CONVDIM + (gcol - DINNER)] = f2bf(v[q]);
                }
            }
        }
    }
}

// ---------------------------------------------------------------------------
// K2: causal depthwise conv1d (width 4) + bias + SiLU
// ---------------------------------------------------------------------------
__global__ __launch_bounds__(256) void conv_silu(
    const __hip_bfloat16* __restrict__ xraw,
    const float* __restrict__ cw, const float* __restrict__ cb,
    __hip_bfloat16* __restrict__ xout)
{
    int idx = blockIdx.x*256 + threadIdx.x;
    if (idx >= BL*CONVDIM) return;
    int c  = idx % CONVDIM;
    int ml = idx / CONVDIM;
    int b  = ml / L_N;
    int l  = ml % L_N;
    const ushort_t* xr = (const ushort_t*)xraw;
    float acc = cb[c];
    #pragma unroll
    for (int k=0;k<DCONV;k++){
        int li = l - (DCONV-1) + k;
        if (li >= 0)
            acc += cw[c*DCONV + k] * bfbits2f(xr[((size_t)b*L_N + li)*CONVDIM + c]);
    }
    float s = acc / (1.f + __expf(-acc));
    xout[idx] = __float2bfloat16(s);
}

// ---------------------------------------------------------------------------
// K3: dA = dt*A; inclusive cumsum within each chunk  (block per (b,h,c))
// ---------------------------------------------------------------------------
__global__ __launch_bounds__(256) void dt_cumsum(
    const float* __restrict__ dtp, const float* __restrict__ A_log,
    float* __restrict__ dAcs)
{
    int blk = blockIdx.x;
    int c  = blk % NCHUNK;
    int bh = blk / NCHUNK;     // b*32 + h
    int h  = bh & (NHEADS-1);
    int t  = threadIdx.x;
    float A = -__expf(A_log[h]);
    __shared__ float sm[CHUNK];
    float v = dtp[(size_t)bh*L_N + c*CHUNK + t] * A;
    sm[t] = v;
    __syncthreads();
    for (int off=1; off<CHUNK; off<<=1){
        float add = (t >= off) ? sm[t-off] : 0.f;
        __syncthreads();
        sm[t] += add;
        __syncthreads();
    }
    dAcs[(size_t)bh*L_N + c*CHUNK + t] = sm[t];
}

// ---------------------------------------------------------------------------
// K4: scoresT[b,c][j][i] = sum_n B[j,n]*C[i,n]   (block per (b,c))
// ---------------------------------------------------------------------------
__global__ __launch_bounds__(256) void bc_scores(
    const __hip_bfloat16* __restrict__ xbc, float* __restrict__ scoresT)
{
    __shared__ uint_t Bsu[CHUNK][DSTATE/2 + 1];   // 66.5 KB
    int bc = blockIdx.x;
    int t  = threadIdx.x;
    const ushort_t* xb = (const ushort_t*)xbc;
    for (int rep=0; rep<64; rep++){
        int idx = rep*256 + t;
        int row = idx >> 6, n2 = idx & 63;
        Bsu[row][n2] = *(const uint_t*)&xb[((size_t)bc*CHUNK + row)*CONVDIM + DINNER + 2*n2];
    }
    __syncthreads();
    int i = t;
    const uint_t* Crow = (const uint_t*)(xb + ((size_t)bc*CHUNK + i)*CONVDIM + DINNER + DSTATE);
    for (int j0=0; j0<CHUNK; j0+=8){
        float acc[8] = {0,0,0,0,0,0,0,0};
        for (int n2=0; n2<DSTATE/2; n2++){
            uint_t cu = Crow[n2];
            float c0 = bflo(cu), c1 = bfhi(cu);
            #pragma unroll
            for (int jj=0;jj<8;jj++){
                uint_t bu = Bsu[j0+jj][n2];
                acc[jj] += c0*bflo(bu) + c1*bfhi(bu);
            }
        }
        #pragma unroll
        for (int jj=0;jj<8;jj++)
            scoresT[((size_t)bc*CHUNK + j0+jj)*CHUNK + i] = acc[jj];
    }
}

// ---------------------------------------------------------------------------
// K5: Y_diag + D*x  (block per (b*c, h); thread = row i)
// ---------------------------------------------------------------------------
__global__ __launch_bounds__(256) void ssd_diag(
    const __hip_bfloat16* __restrict__ xbc,
    const float* __restrict__ dtp, const float* __restrict__ dAcs,
    const float* __restrict__ scoresT, const float* __restrict__ D_param,
    float* __restrict__ yh)
{
    __shared__ float xs[CHUNK][HEADDIM+4];
    __shared__ float dt_s[CHUNK];
    __shared__ float da_s[CHUNK];
    int bc = blockIdx.x, h = blockIdx.y;
    int b = bc >> 3, c = bc & 7;
    int t = threadIdx.x;
    const ushort_t* xb = (const ushort_t*)xbc;
    for (int rep=0; rep<64; rep++){
        int idx = rep*256 + t;
        int row = idx >> 6, pp = idx & 63;
        xs[row][pp] = bfbits2f(xb[((size_t)bc*CHUNK + row)*CONVDIM + h*HEADDIM + pp]);
    }
    dt_s[t] = dtp[((size_t)b*NHEADS + h)*L_N + c*CHUNK + t];
    da_s[t] = dAcs[((size_t)b*NHEADS + h)*L_N + c*CHUNK + t];
    __syncthreads();
    int i = t;
    float acc[64];
    #pragma unroll
    for (int q=0;q<64;q++) acc[q]=0.f;
    float myda = da_s[i];
    const float* srow = scoresT + (size_t)bc*CHUNK*CHUNK + i;
    for (int j=0; j<=i; j++){
        float w = __expf(myda - da_s[j]) * dt_s[j] * srow[(size_t)j*CHUNK];
        const float4* xr = (const float4*)&xs[j][0];
        #pragma unroll
        for (int q=0;q<16;q++){
            float4 xv = xr[q];
            acc[4*q+0] += w*xv.x; acc[4*q+1] += w*xv.y;
            acc[4*q+2] += w*xv.z; acc[4*q+3] += w*xv.w;
        }
    }
    float Dh = D_param[h];
    size_t row = ((size_t)bc*CHUNK + i)*DINNER + (size_t)h*HEADDIM;
    #pragma unroll
    for (int q=0;q<64;q++) yh[row+q] = acc[q] + Dh*xs[i][q];
}

// ---------------------------------------------------------------------------
// K6: chunk states[b,c,h,p,n] = sum_j B[j,n]*exp(da_last-da[j])*dt[j]*x[j,p]
// ---------------------------------------------------------------------------
__global__ __launch_bounds__(256) void ssd_states(
    const __hip_bfloat16* __restrict__ xbc,
    const float* __restrict__ dtp, const float* __restrict__ dAcs,
    float* __restrict__ states)
{
    __shared__ uint_t Bsu[CHUNK][DSTATE/2];   // 64 KB
    __shared__ float dt_s[CHUNK];
    __shared__ float da_s[CHUNK];
    int bc = blockIdx.x, h = blockIdx.y;
    int b = bc >> 3, c = bc & 7;
    int t = threadIdx.x;
    const ushort_t* xb = (const ushort_t*)xbc;
    for (int rep=0; rep<64; rep++){
        int idx = rep*256 + t;
        int row = idx >> 6, n2 = idx & 63;
        Bsu[row][n2] = *(const uint_t*)&xb[((size_t)bc*CHUNK + row)*CONVDIM + DINNER + 2*n2];
    }
    dt_s[t] = dtp[((size_t)b*NHEADS + h)*L_N + c*CHUNK + t];
    da_s[t] = dAcs[((size_t)b*NHEADS + h)*L_N + c*CHUNK + t];
    __syncthreads();
    int p = t & 63, ng = t >> 6;
    float sacc[32];
    #pragma unroll
    for (int q=0;q<32;q++) sacc[q]=0.f;
    float last = da_s[CHUNK-1];
    for (int j=0;j<CHUNK;j++){
        float xv = bfbits2f(xb[((size_t)bc*CHUNK + j)*CONVDIM + h*HEADDIM + p]);
        float coef = __expf(last - da_s[j]) * dt_s[j] * xv;
        const uint_t* br = &Bsu[j][ng*16];
        #pragma unroll
        for (int k2=0;k2<16;k2++){
            uint_t bu = br[k2];
            sacc[2*k2]   += coef*bflo(bu);
            sacc[2*k2+1] += coef*bfhi(bu);
        }
    }
    size_t sb = (((size_t)bc*NHEADS + h)*HEADDIM + p)*DSTATE + ng*32;
    #pragma unroll
    for (int q=0;q<32;q++) states[sb+q] = sacc[q];
}

// ---------------------------------------------------------------------------
// K7: inter-chunk scan (sequential over 8 chunks), in-place: states -> prev
// ---------------------------------------------------------------------------
__global__ __launch_bounds__(256) void scan_states(
    float* __restrict__ states, const float* __restrict__ dAcs)
{
    int idx = blockIdx.x*256 + threadIdx.x;   // ((b*32+h)*64+p)*128+n
    int n  = idx & 127;
    int p  = (idx >> 7) & 63;
    int bh = idx >> 13;
    int b  = bh >> 5, h = bh & 31;
    float carry = 0.f;
    for (int c=0;c<NCHUNK;c++){
        size_t off = (((size_t)((b*NCHUNK + c)*NHEADS + h))*HEADDIM + p)*DSTATE + n;
        float s = states[off];
        states[off] = carry;
        float cd = __expf(dAcs[((size_t)b*NHEADS + h)*L_N + c*CHUNK + (CHUNK-1)]);
        carry = carry * cd + s;
    }
}

// ---------------------------------------------------------------------------
// K8: Y_off[i,p] = exp(da[i]) * sum_n C[i,n]*prev[p,n];  yh += Y_off
// ---------------------------------------------------------------------------
__global__ __launch_bounds__(256) void ssd_off(
    const __hip_bfloat16* __restrict__ xbc,
    const float* __restrict__ dAcs, const float* __restrict__ states,
    float* __restrict__ yh)
{
    __shared__ float ps[HEADDIM][DSTATE];   // 32 KB
    int bc = blockIdx.x, h = blockIdx.y;
    int b = bc >> 3, c = bc & 7;
    int t = threadIdx.x;
    const float* sb = states + (size_t)(bc*NHEADS + h)*HEADDIM*DSTATE;
    for (int rep=0; rep<32; rep++){
        int idx = rep*256 + t;
        ((float*)ps)[idx] = sb[idx];
    }
    __syncthreads();
    int i = t;
    float acc[64];
    #pragma unroll
    for (int q=0;q<64;q++) acc[q]=0.f;
    const ushort_t* xb = (const ushort_t*)xbc;
    const uint_t* Crow = (const uint_t*)(xb + ((size_t)bc*CHUNK + i)*CONVDIM + DINNER + DSTATE);
    #pragma unroll
    for (int nb=0; nb<4; nb++){
        float cv[32];
        #pragma unroll
        for (int k2=0;k2<16;k2++){
            uint_t u = Crow[nb*16 + k2];
            cv[2*k2] = bflo(u); cv[2*k2+1] = bfhi(u);
        }
        #pragma unroll
        for (int p=0;p<64;p++){
            const float4* pr = (const float4*)&ps[p][nb*32];
            float s = 0.f;
            #pragma unroll
            for (int k4=0;k4<8;k4++){
                float4 v = pr[k4];
                s += cv[4*k4]*v.x + cv[4*k4+1]*v.y + cv[4*k4+2]*v.z + cv[4*k4+3]*v.w;
            }
            acc[p] += s;
        }
    }
    float scale = __expf(dAcs[((size_t)b*NHEADS + h)*L_N + c*CHUNK + i]);
    size_t row = ((size_t)bc*CHUNK + i)*DINNER + (size_t)h*HEADDIM;
    #pragma unroll
    for (int q=0;q<64;q++) yh[row+q] += scale*acc[q];
}

// ---------------------------------------------------------------------------
// K9: g = yh * silu(z); RMSNorm(g)*norm_w  -> bf16 g  (block per token row)
// ---------------------------------------------------------------------------
__global__ __launch_bounds__(256) void gate_norm(
    const float* __restrict__ yh, const __hip_bfloat16* __restrict__ z,
    const float* __restrict__ norm_w, __hip_bfloat16* __restrict__ g)
{
    int row = blockIdx.x;
    int t = threadIdx.x;
    const float* yr = yh + (size_t)row*DINNER;
    const ushort_t* zr = (const ushort_t*)z + (size_t)row*DINNER;
    float v[8];
    float ss = 0.f;
    #pragma unroll
    for (int r=0;r<8;r++){
        int d = r*256 + t;
        float zv = bfbits2f(zr[d]);
        float gv = yr[d] * (zv / (1.f + __expf(-zv)));
        v[r] = gv; ss += gv*gv;
    }
    #pragma unroll
    for (int off=32; off>=1; off>>=1) ss += __shfl_xor(ss, off);
    __shared__ float red[4];
    if ((t & 63) == 0) red[t >> 6] = ss;
    __syncthreads();
    float tot = red[0]+red[1]+red[2]+red[3];
    float scale = rsqrtf(tot * (1.f/DINNER) + 1e-5f);
    __hip_bfloat16* gr = g + (size_t)row*DINNER;
    #pragma unroll
    for (int r=0;r<8;r++){
        int d = r*256 + t;
        gr[d] = __float2bfloat16(v[r]*scale*norm_w[d]);
    }
}

// ---------------------------------------------------------------------------
extern "C" void kernel_launch(void* const* d_in, const int* in_sizes, int n_in,
                              void* d_out, int out_size, void* d_ws, size_t ws_size,
                              hipStream_t stream)
{
    const float* u       = (const float*)d_in[0];
    const float* W_in    = (const float*)d_in[1];
    const float* conv_w  = (const float*)d_in[2];
    const float* conv_b  = (const float*)d_in[3];
    const float* dt_bias = (const float*)d_in[4];
    const float* A_log   = (const float*)d_in[5];
    const float* D_param = (const float*)d_in[6];
    const float* norm_w  = (const float*)d_in[7];
    const float* W_out   = (const float*)d_in[8];
    float* out = (float*)d_out;

    char* p = (char*)d_ws;
    auto take = [&](size_t n){ char* r = p; p += (n + 255) & ~(size_t)255; return r; };

    __hip_bfloat16* z       = (__hip_bfloat16*)take((size_t)BL*DINNER*2);
    __hip_bfloat16* xbc_raw = (__hip_bfloat16*)take((size_t)BL*CONVDIM*2);
    __hip_bfloat16* xbc     = (__hip_bfloat16*)take((size_t)BL*CONVDIM*2);
    float* dtp     = (float*)take((size_t)BL*NHEADS*4);
    float* dAcs    = (float*)take((size_t)BL*NHEADS*4);
    float* scoresT = (float*)take((size_t)B_N*NCHUNK*CHUNK*CHUNK*4);
    float* states  = (float*)take((size_t)B_N*NCHUNK*NHEADS*HEADDIM*DSTATE*4);
    float* yh      = (float*)take((size_t)BL*DINNER*4);
    ushort_t* u_bf  = (ushort_t*)take((size_t)BL*DMODEL*2);
    ushort_t* Wi_bf = (ushort_t*)take((size_t)(DINNER+CONVDIM)*DMODEL*2);
    ushort_t* Wo_bf = (ushort_t*)take((size_t)DMODEL*DINNER*2);
    __hip_bfloat16* g = z;   // alias: z dead after gate_norm's elementwise read

    // converts
    cvt_bf16<<<dim3((BL*DMODEL/8 + 255)/256), 256, 0, stream>>>(u, u_bf, BL*DMODEL/8);
    cvt_bf16<<<dim3(((DINNER+CONVDIM)*DMODEL/8 + 255)/256), 256, 0, stream>>>(W_in, Wi_bf, (DINNER+CONVDIM)*DMODEL/8);
    cvt_bf16<<<dim3((DMODEL*DINNER/8 + 255)/256), 256, 0, stream>>>(W_out, Wo_bf, DMODEL*DINNER/8);

    // dt columns in fp32
    dt_gemm<<<dim3(BL*NHEADS/256), 256, 0, stream>>>(u, W_in, dt_bias, dtp);

    // in-proj (z + xBC sections): N = 4352 = 34 * 128
    gemm_bt_mfma<DMODEL,1><<<dim3(BL/128, (DINNER+CONVDIM)/128), 256, 0, stream>>>(
        u_bf, Wi_bf, nullptr, (ushort_t*)z, (ushort_t*)xbc_raw);

    conv_silu<<<dim3((BL*CONVDIM)/256), 256, 0, stream>>>(xbc_raw, conv_w, conv_b, xbc);
    dt_cumsum<<<dim3(B_N*NHEADS*NCHUNK), 256, 0, stream>>>(dtp, A_log, dAcs);
    bc_scores<<<dim3(B_N*NCHUNK), 256, 0, stream>>>(xbc, scoresT);
    ssd_diag<<<dim3(B_N*NCHUNK, NHEADS), 256, 0, stream>>>(xbc, dtp, dAcs, scoresT, D_param, yh);
    ssd_states<<<dim3(B_N*NCHUNK, NHEADS), 256, 0, stream>>>(xbc, dtp, dAcs, states);
    scan_states<<<dim3((B_N*NHEADS*HEADDIM*DSTATE)/256), 256, 0, stream>>>(states, dAcs);
    ssd_off<<<dim3(B_N*NCHUNK, NHEADS), 256, 0, stream>>>(xbc, dAcs, states, yh);
    gate_norm<<<dim3(BL), 256, 0, stream>>>(yh, z, norm_w, g);

    // out-proj
    gemm_bt_mfma<DINNER,0><<<dim3(BL/128, DMODEL/128), 256, 0, stream>>>(
        (const ushort_t*)g, Wo_bf, out, nullptr, nullptr);
}